// Round 1
// baseline (818.872 us; speedup 1.0000x reference)
//
#include <hip/hip_runtime.h>
#include <cstddef>
#include <cstdint>

// Problem constants: EMBED=1024, NUM_HEADS=16, GQA=4, KV_HEADS=4,
// HEAD_DIM=64, KV_EMBED=256, EPS=1e-3, B=2, T=1024.
#define TSEQ 1024

typedef __attribute__((ext_vector_type(8))) short short8;   // 8 bf16 = 4 VGPRs
typedef __attribute__((ext_vector_type(4))) float floatx4;  // MFMA acc

// Workspace layout (floats):
//  XQ : 2048 x 1024  (2M)
//  XK : 2048 x 256   (0.5M)
//  XVt: 2 x 256 x 1024 (0.5M)  -- V-projection TRANSPOSED: [b][h*64+c][j]
//  XO : 2048 x 1024  (2M)
//  P  : 32 x 1024x1024 (33.55M) -- probs, overwritten in place by phi
static constexpr size_t OFF_XQ  = 0;
static constexpr size_t OFF_XK  = (size_t)2 * 1024 * 1024;
static constexpr size_t OFF_XVT = OFF_XK + (size_t)512 * 1024;
static constexpr size_t OFF_XO  = OFF_XVT + (size_t)512 * 1024;
static constexpr size_t OFF_P   = OFF_XO + (size_t)2 * 1024 * 1024;

// ---------------------------------------------------------------------------
// fp32 -> bf16 hi/lo split (RNE). x ≈ hi + lo with residual ~2^-17 |x|.
// ---------------------------------------------------------------------------
__device__ __forceinline__ void cvt_hi_lo(float x, unsigned short& hi,
                                          unsigned short& lo) {
  unsigned u = __float_as_uint(x);
  unsigned rh = (u + 0x7FFFu + ((u >> 16) & 1u)) & 0xFFFF0000u;
  hi = (unsigned short)(rh >> 16);
  float xl = x - __uint_as_float(rh);
  unsigned ul = __float_as_uint(xl);
  unsigned rl = ul + 0x7FFFu + ((ul >> 16) & 1u);
  lo = (unsigned short)(rl >> 16);
}

// ---------------------------------------------------------------------------
// Unified NT GEMM core, MFMA bf16x3 (R5-proven, do not touch).
// ---------------------------------------------------------------------------
template <int EPI>
__device__ __forceinline__ void mfma_nt_core(
    const float* __restrict__ A, int lda,
    const float* __restrict__ B, int ldb,
    float* __restrict__ C, int ldc, int K,
    const float* __restrict__ bias)
{
  __shared__ __align__(16) unsigned short Ah[64][40];
  __shared__ __align__(16) unsigned short Al[64][40];
  __shared__ __align__(16) unsigned short Bh[64][40];
  __shared__ __align__(16) unsigned short Bl[64][40];

  const int bm = blockIdx.y << 6;
  const int bn = blockIdx.x << 6;
  const int tid  = threadIdx.x;
  const int lane = tid & 63;
  const int wave = tid >> 6;        // 0..3 -> row sub-tile
  const int m16  = lane & 15;
  const int quad = lane >> 4;

  const int srow = tid >> 2;        // staging: row 0..63
  const int skq  = (tid & 3) << 3;  // staging: k offset 0,8,16,24

  floatx4 acc[4];
#pragma unroll
  for (int c = 0; c < 4; ++c) acc[c] = (floatx4){0.f, 0.f, 0.f, 0.f};

  for (int k0 = 0; k0 < K; k0 += 32) {
    {
      const float* ap = A + (size_t)(bm + srow) * lda + (k0 + skq);
      const float* bp = B + (size_t)(bn + srow) * ldb + (k0 + skq);
      float av[8] __attribute__((aligned(16)));
      float bv[8] __attribute__((aligned(16)));
      *(float4*)&av[0] = *(const float4*)(ap);
      *(float4*)&av[4] = *(const float4*)(ap + 4);
      *(float4*)&bv[0] = *(const float4*)(bp);
      *(float4*)&bv[4] = *(const float4*)(bp + 4);
      short8 vah, valo, vbh, vblo;
#pragma unroll
      for (int e = 0; e < 8; ++e) {
        unsigned short h, l;
        cvt_hi_lo(av[e], h, l);
        vah[e] = (short)h; valo[e] = (short)l;
        cvt_hi_lo(bv[e], h, l);
        vbh[e] = (short)h; vblo[e] = (short)l;
      }
      *(short8*)&Ah[srow][skq] = vah;
      *(short8*)&Al[srow][skq] = valo;
      *(short8*)&Bh[srow][skq] = vbh;
      *(short8*)&Bl[srow][skq] = vblo;
    }
    __syncthreads();

    const int arow = (wave << 4) + m16;
    const short8 a_h = *(const short8*)&Ah[arow][quad << 3];
    const short8 a_l = *(const short8*)&Al[arow][quad << 3];
#pragma unroll
    for (int c = 0; c < 4; ++c) {
      const int brow = (c << 4) + m16;
      const short8 b_h = *(const short8*)&Bh[brow][quad << 3];
      const short8 b_l = *(const short8*)&Bl[brow][quad << 3];
      acc[c] = __builtin_amdgcn_mfma_f32_16x16x32_bf16(a_h, b_h, acc[c], 0, 0, 0);
      acc[c] = __builtin_amdgcn_mfma_f32_16x16x32_bf16(a_h, b_l, acc[c], 0, 0, 0);
      acc[c] = __builtin_amdgcn_mfma_f32_16x16x32_bf16(a_l, b_h, acc[c], 0, 0, 0);
    }
    __syncthreads();
  }

#pragma unroll
  for (int c = 0; c < 4; ++c) {
#pragma unroll
    for (int r = 0; r < 4; ++r) {
      const int row = (wave << 4) + (quad << 2) + r;
      const int col = (c << 4) + m16;
      float v = acc[c][r];
      if (EPI == 0) { if (bias) v += bias[bn + col]; }
      if (EPI == 1) { v += bias[bm + row]; }
      if (EPI == 2) {
        v = 1.0f / (1.0f + expf(-v));
        v = fminf(fmaxf(v, 0.001f), 0.999f);
      }
      C[(size_t)(bm + row) * ldc + (bn + col)] = v;
    }
  }
}

__global__ __launch_bounds__(256) void gemm_nt_mfma_k(
    const float* __restrict__ A, int lda, const float* __restrict__ W, int ldw,
    const float* __restrict__ bias, float* __restrict__ C, int ldc, int K)
{
  mfma_nt_core<0>(A, lda, W, ldw, C, ldc, K, bias);
}

__global__ __launch_bounds__(256) void proj_vt_k(
    const float* __restrict__ vw, const float* __restrict__ value,
    const float* __restrict__ vb, float* __restrict__ XVt)
{
  const int b = blockIdx.z;
  mfma_nt_core<1>(vw, 1024, value + ((size_t)b << 20), 1024,
                  XVt + (size_t)b * 256 * 1024, 1024, 1024, vb);
}

__global__ __launch_bounds__(256) void scores_mfma_k(
    const float* __restrict__ XQ, const float* __restrict__ XK,
    float* __restrict__ P)
{
  const int z = blockIdx.z;
  const int b = z >> 4;
  mfma_nt_core<2>(XQ + ((size_t)b << 20) + ((size_t)(z & 15) << 6), 1024,
                  XK + (size_t)b * TSEQ * 256 + ((size_t)(z & 3) << 6), 256,
                  P + ((size_t)z << 20), 1024, 64, nullptr);
}

__global__ __launch_bounds__(256) void pv_mfma_k(
    const float* __restrict__ P, const float* __restrict__ XVt,
    float* __restrict__ XO)
{
  const int z = blockIdx.z;
  const int b = z >> 4;
  mfma_nt_core<0>(P + ((size_t)z << 20), 1024,
                  XVt + (size_t)b * 256 * 1024 + (size_t)(z & 3) * 64 * 1024, 1024,
                  XO + ((size_t)b << 20) + ((size_t)(z & 15) << 6), 1024,
                  1024, nullptr);
}

// ---------------------------------------------------------------------------
// Monotonic recurrence, in place over P (probs -> phi). ONE WAVE per z.
// Lane t owns columns [16t,16t+16). Cross-lane = __shfl_up / readlane ONLY
// (R2-proven; DPP failed 3x on gfx950 -- permanently banned here).
//
// FOUR ROWS PER PASS (R6): state s_j = (phi[i..i+3, j]) obeys
//   s_j = M_j s_{j-1} + c_j with lower-triangular 4x4
//   M_j = [[H,0,0,0],[qH,G,0,0],[rqH,rG,F,0],[srqH,srG,sF,E]],
//   H=1-p[i,j-1], G=1-p[i+1,j-1], F=1-p[i+2,j-1], E=1-p[i+3,j-1],
//   q=p[i,j], r=p[i+1,j], s=p[i+2,j],  c_j = b_j*(1,q,rq,srq),
//   b_j = p[i-1,j]*phi[i-1,j] (the carry).
// Affine maps tracked as 10 matrix entries (a,e,f,g,h,i,j,k,l,m row-major
// lower tri) + 4 vector entries (bx,by,bz,bw). Incremental per-column
// update costs 14 FMA-class ops (exact 4x4 generalization of the proven
// 2x2 update). Cross-lane: 5-stage Kogge-Stone WITHIN 32-lane halves +
// one readlane(31) SGPR-broadcast compose for the upper half (saves one
// ds_bpermute round-trip vs the 6-stage full-64 scan). The number of
// latency-bound scan stages per 4 rows drops 12 -> 5+eps vs the 2-row
// version; pass count 512 -> 256.
// Rows 0,1 and the final pair (1022,1023) keep the proven 1/2-row code.
// In-place safety: pass i reads prefetched rows i+4..i+7, writes rows
// i..i+3 -- disjoint; lanes are lockstep within the single wave.
// ---------------------------------------------------------------------------
__device__ __forceinline__ float rdl31(float v) {
  return __int_as_float(__builtin_amdgcn_readlane(__float_as_int(v), 31));
}

__global__ __launch_bounds__(64) void mono_rec_k(float* __restrict__ P)
{
  const int z = blockIdx.x;
  float* __restrict__ Pz = P + ((size_t)z << 20);
  const int t = threadIdx.x;     // lane 0..63
  const int col0 = t << 4;       // first owned column
  const int bofs = (t == 0) ? 0 : (col0 - 1);   // boundary col (dummy at t=0)

  float b[16];                   // u-carry: b_c = phi[i-1,c]*p[i-1,c]

  // --- row 0: phi = onehot(0); b = phi0 * p_row0 (only col 0 nonzero) ---
  const float p00 = Pz[0];       // read BEFORE overwriting row 0 in place
  {
    float4 z4 = make_float4(0.f, 0.f, 0.f, 0.f);
    float4 v0 = z4;
    if (t == 0) v0.x = 1.0f;
    *(float4*)(Pz + col0 + 0)  = v0;
    *(float4*)(Pz + col0 + 4)  = z4;
    *(float4*)(Pz + col0 + 8)  = z4;
    *(float4*)(Pz + col0 + 12) = z4;
  }
#pragma unroll
  for (int c = 0; c < 16; ++c) b[c] = 0.0f;
  if (t == 0) b[0] = p00;

  // --- row 1: single-row step (R2-proven scalar affine scan) ---
  {
    float pu1[16];
#pragma unroll
    for (int q = 0; q < 4; ++q)
      *(float4*)&pu1[4 * q] = *(const float4*)(Pz + ((size_t)1 << 10) + col0 + 4 * q);

    const float pl = __shfl_up(pu1[15], 1);
    const float A0 = (t == 0) ? 0.0f : (1.0f - pl);
    float SA[16], SB[16];
    SA[0] = A0;
    SB[0] = b[0];
#pragma unroll
    for (int c = 1; c < 16; ++c) {
      const float Ac = 1.0f - pu1[c - 1];
      SA[c] = SA[c - 1] * Ac;
      SB[c] = fmaf(SB[c - 1], Ac, b[c]);
    }
    float tA = SA[15], tB = SB[15];
#pragma unroll
    for (int off = 1; off < 64; off <<= 1) {
      const float uA = __shfl_up(tA, off);
      const float uB = __shfl_up(tB, off);
      if (t >= off) { tB = fmaf(uB, tA, tB); tA = uA * tA; }
    }
    float pB = __shfl_up(tB, 1);
    if (t == 0) pB = 0.0f;
    float phin[16];
#pragma unroll
    for (int c = 0; c < 16; ++c) {
      phin[c] = fmaf(pB, SA[c], SB[c]);
      b[c] = phin[c] * pu1[c];
    }
    float* rowp = Pz + ((size_t)1 << 10) + col0;
#pragma unroll
    for (int q = 0; q < 4; ++q)
      *(float4*)(rowp + 4 * q) = *(float4*)&phin[4 * q];
  }

  // --- quad passes: rows (2..5), (6..9), ..., (1018..1021): 255 passes ---
  float bufA[4][16], bufB[4][16];   // ping-pong quad buffers (p-values)
  float qA[4], qB[4];               // boundary values p[row, col0-1]

  // preload rows 2..5 + boundaries
#pragma unroll
  for (int r = 0; r < 4; ++r) {
    const size_t ro = (size_t)(2 + r) << 10;
#pragma unroll
    for (int q = 0; q < 4; ++q)
      *(float4*)&bufA[r][4 * q] = *(const float4*)(Pz + ro + col0 + 4 * q);
    qA[r] = Pz[ro + bofs];
  }

  auto pass4 = [&](int i, float (&up)[4][16], const float (&qu)[4],
                   float (&wn)[4][16], float (&qn)[4]) {
    // prefetch rows i+4..i+7 (+boundaries); clamped loads never consumed
#pragma unroll
    for (int r = 0; r < 4; ++r) {
      const int rowc = (i + 4 + r < TSEQ) ? (i + 4 + r) : (TSEQ - 1);
      const size_t ro = (size_t)rowc << 10;
#pragma unroll
      for (int q = 0; q < 4; ++q)
        *(float4*)&wn[r][4 * q] = *(const float4*)(Pz + ro + col0 + 4 * q);
      qn[r] = Pz[ro + bofs];
    }

    // boundary coefficients; global col 0 -> 0
    const float H0 = (t == 0) ? 0.0f : (1.0f - qu[0]);
    const float G0 = (t == 0) ? 0.0f : (1.0f - qu[1]);
    const float F0 = (t == 0) ? 0.0f : (1.0f - qu[2]);
    const float E0 = (t == 0) ? 0.0f : (1.0f - qu[3]);

    // lane-total affine map over own 16 columns.
    // matrix (lower tri, row-major): a; e f; g h i_; j_ k l m_  + vec bx..bw
    float a = H0, f = G0, i_ = F0, m_ = E0;
    {
      // column 0 (map = M_0, vec = c_0)
      const float q0 = up[0][0], r0 = up[1][0], s0 = up[2][0];
      float e0 = q0 * a;
      float g0 = r0 * e0, h0 = r0 * f;
      float j0 = s0 * g0, k0 = s0 * h0, l0 = s0 * i_;
      float bx0 = b[0];
      float by0 = q0 * bx0;
      float bz0 = r0 * by0;
      float bw0 = s0 * bz0;
      // fold columns 1..15
      float e = e0, g = g0, h = h0, j_ = j0, k = k0, l = l0;
      float bx = bx0, by = by0, bz = bz0, bw = bw0;
#pragma unroll
      for (int c = 1; c < 16; ++c) {
        const float H  = 1.0f - up[0][c - 1];
        const float G  = 1.0f - up[1][c - 1];
        const float F  = 1.0f - up[2][c - 1];
        const float E  = 1.0f - up[3][c - 1];
        const float qq = up[0][c];
        const float rr = up[1][c];
        const float ss = up[2][c];
        a  = H * a;
        e  = fmaf(G, e, qq * a);     // uses NEW a
        f  = G * f;
        g  = fmaf(F, g, rr * e);     // uses NEW e
        h  = fmaf(F, h, rr * f);     // uses NEW f
        i_ = F * i_;
        j_ = fmaf(E, j_, ss * g);    // uses NEW g
        k  = fmaf(E, k, ss * h);     // uses NEW h
        l  = fmaf(E, l, ss * i_);    // uses NEW i_
        m_ = E * m_;
        bx = fmaf(H, bx, b[c]);
        by = fmaf(G, by, qq * bx);
        bz = fmaf(F, bz, rr * by);
        bw = fmaf(E, bw, ss * bz);
      }

      // 5-stage Kogge-Stone within 32-lane halves (cur ∘ up)
#pragma unroll
      for (int off = 1; off < 32; off <<= 1) {
        const float ua  = __shfl_up(a, off);
        const float ue  = __shfl_up(e, off);
        const float uf  = __shfl_up(f, off);
        const float ug  = __shfl_up(g, off);
        const float uh  = __shfl_up(h, off);
        const float ui  = __shfl_up(i_, off);
        const float uj  = __shfl_up(j_, off);
        const float uk  = __shfl_up(k, off);
        const float ul  = __shfl_up(l, off);
        const float um  = __shfl_up(m_, off);
        const float ubx = __shfl_up(bx, off);
        const float uby = __shfl_up(by, off);
        const float ubz = __shfl_up(bz, off);
        const float ubw = __shfl_up(bw, off);
        if ((t & 31) >= off) {
          const float na  = a * ua;
          const float ne  = fmaf(e, ua, f * ue);
          const float nf  = f * uf;
          const float ng  = fmaf(g, ua, fmaf(h, ue, i_ * ug));
          const float nh  = fmaf(h, uf, i_ * uh);
          const float ni  = i_ * ui;
          const float nj  = fmaf(j_, ua, fmaf(k, ue, fmaf(l, ug, m_ * uj)));
          const float nk  = fmaf(k, uf, fmaf(l, uh, m_ * uk));
          const float nl  = fmaf(l, ui, m_ * ul);
          const float nm  = m_ * um;
          const float nbx = fmaf(a, ubx, bx);
          const float nby = fmaf(e, ubx, fmaf(f, uby, by));
          const float nbz = fmaf(g, ubx, fmaf(h, uby, fmaf(i_, ubz, bz)));
          const float nbw = fmaf(j_, ubx, fmaf(k, uby, fmaf(l, ubz, fmaf(m_, ubw, bw))));
          a = na; e = ne; f = nf; g = ng; h = nh; i_ = ni;
          j_ = nj; k = nk; l = nl; m_ = nm;
          bx = nbx; by = nby; bz = nbz; bw = nbw;
        }
      }
      // broadcast lower-half total (lane 31) to upper half via readlane (SGPR)
      {
        const float ua  = rdl31(a);
        const float ue  = rdl31(e);
        const float uf  = rdl31(f);
        const float ug  = rdl31(g);
        const float uh  = rdl31(h);
        const float ui  = rdl31(i_);
        const float uj  = rdl31(j_);
        const float uk  = rdl31(k);
        const float ul  = rdl31(l);
        const float um  = rdl31(m_);
        const float ubx = rdl31(bx);
        const float uby = rdl31(by);
        const float ubz = rdl31(bz);
        const float ubw = rdl31(bw);
        if (t >= 32) {
          const float na  = a * ua;
          const float ne  = fmaf(e, ua, f * ue);
          const float nf  = f * uf;
          const float ng  = fmaf(g, ua, fmaf(h, ue, i_ * ug));
          const float nh  = fmaf(h, uf, i_ * uh);
          const float ni  = i_ * ui;
          const float nj  = fmaf(j_, ua, fmaf(k, ue, fmaf(l, ug, m_ * uj)));
          const float nk  = fmaf(k, uf, fmaf(l, uh, m_ * uk));
          const float nl  = fmaf(l, ui, m_ * ul);
          const float nm  = m_ * um;
          const float nbx = fmaf(a, ubx, bx);
          const float nby = fmaf(e, ubx, fmaf(f, uby, by));
          const float nbz = fmaf(g, ubx, fmaf(h, uby, fmaf(i_, ubz, bz)));
          const float nbw = fmaf(j_, ubx, fmaf(k, uby, fmaf(l, ubz, fmaf(m_, ubw, bw))));
          a = na; e = ne; f = nf; g = ng; h = nh; i_ = ni;
          j_ = nj; k = nk; l = nl; m_ = nm;
          bx = nbx; by = nby; bz = nbz; bw = nbw;
        }
      }

      // exclusive incoming state for this lane (global start state = 0)
      float Xx = __shfl_up(bx, 1);
      float Xy = __shfl_up(by, 1);
      float Xz = __shfl_up(bz, 1);
      float Xw = __shfl_up(bw, 1);
      if (t == 0) { Xx = 0.f; Xy = 0.f; Xz = 0.f; Xw = 0.f; }

      // re-run local recurrence with incoming state; build next b-carry;
      // store per-quad to keep register pressure down.
      float x = fmaf(H0, Xx, b[0]);
      float y = fmaf(G0, Xy, up[0][0] * x);
      float zz2 = fmaf(F0, Xz, up[1][0] * y);
      float ww2 = fmaf(E0, Xw, up[2][0] * zz2);
      b[0] = ww2 * up[3][0];
      float* r0p = Pz + ((size_t)i << 10) + col0;
#pragma unroll
      for (int qd = 0; qd < 4; ++qd) {
        float vx[4], vy[4], vz[4], vw[4];
#pragma unroll
        for (int c2 = 0; c2 < 4; ++c2) {
          const int c = (qd << 2) + c2;
          if (c > 0) {
            x   = fmaf(1.0f - up[0][c - 1], x, b[c]);
            y   = fmaf(1.0f - up[1][c - 1], y, up[0][c] * x);
            zz2 = fmaf(1.0f - up[2][c - 1], zz2, up[1][c] * y);
            ww2 = fmaf(1.0f - up[3][c - 1], ww2, up[2][c] * zz2);
            b[c] = ww2 * up[3][c];
          }
          vx[c2] = x; vy[c2] = y; vz[c2] = zz2; vw[c2] = ww2;
        }
        *(float4*)(r0p + 0 * TSEQ + (qd << 2)) = *(float4*)&vx[0];
        *(float4*)(r0p + 1 * TSEQ + (qd << 2)) = *(float4*)&vy[0];
        *(float4*)(r0p + 2 * TSEQ + (qd << 2)) = *(float4*)&vz[0];
        *(float4*)(r0p + 3 * TSEQ + (qd << 2)) = *(float4*)&vw[0];
      }
    }
  };

  // 127 ping-pong rounds (254 passes, i=2..1014) + pass i=1018 + pair 1022
  int i = 2;
  for (int kk = 0; kk < 127; ++kk) {
    pass4(i, bufA, qA, bufB, qB);
    pass4(i + 4, bufB, qB, bufA, qA);
    i += 8;
  }
  pass4(1018, bufA, qA, bufB, qB);  // prefetches rows 1022,1023(,clamps) -> bufB

  // --- final pair (1022,1023): R5-proven 2-row pass, no prefetch ---
  {
    const float* up = bufB[0];
    const float* vp = bufB[1];
    const float qu = qB[0];
    const float qv = qB[1];

    const float H0 = (t == 0) ? 0.0f : (1.0f - qu);
    const float G0 = (t == 0) ? 0.0f : (1.0f - qv);

    float a = H0, d = G0;
    float bx = b[0];
    float cc = up[0] * a;
    float by = up[0] * bx;
#pragma unroll
    for (int c = 1; c < 16; ++c) {
      const float H  = 1.0f - up[c - 1];
      const float G  = 1.0f - vp[c - 1];
      const float qq = up[c];
      a  = H * a;
      bx = fmaf(H, bx, b[c]);
      cc = fmaf(G, cc, qq * a);
      by = fmaf(G, by, qq * bx);
      d  = G * d;
    }
#pragma unroll
    for (int off = 1; off < 64; off <<= 1) {
      const float ua  = __shfl_up(a, off);
      const float ucc = __shfl_up(cc, off);
      const float ud  = __shfl_up(d, off);
      const float ubx = __shfl_up(bx, off);
      const float uby = __shfl_up(by, off);
      if (t >= off) {
        const float nbx = fmaf(a, ubx, bx);
        const float nby = fmaf(cc, ubx, fmaf(d, uby, by));
        const float ncc = fmaf(cc, ua, d * ucc);
        a = a * ua;
        d = d * ud;
        bx = nbx; by = nby; cc = ncc;
      }
    }
    float Xx = __shfl_up(bx, 1);
    float Xy = __shfl_up(by, 1);
    if (t == 0) { Xx = 0.0f; Xy = 0.0f; }

    float xa[16], ya[16];
    float x = fmaf(H0, Xx, b[0]);
    float y = fmaf(G0, Xy, up[0] * x);
    xa[0] = x; ya[0] = y;
#pragma unroll
    for (int c = 1; c < 16; ++c) {
      x = fmaf(1.0f - up[c - 1], x, b[c]);
      y = fmaf(1.0f - vp[c - 1], y, up[c] * x);
      xa[c] = x; ya[c] = y;
    }
    float* rowu = Pz + ((size_t)1022 << 10) + col0;
    float* rowv = rowu + TSEQ;
#pragma unroll
    for (int q = 0; q < 4; ++q) {
      *(float4*)(rowu + 4 * q) = *(float4*)&xa[4 * q];
      *(float4*)(rowv + 4 * q) = *(float4*)&ya[4 * q];
    }
  }
}

// ---------------------------------------------------------------------------
extern "C" void kernel_launch(void* const* d_in, const int* in_sizes, int n_in,
                              void* d_out, int out_size, void* d_ws, size_t ws_size,
                              hipStream_t stream)
{
  const float* query = (const float*)d_in[0];
  const float* key   = (const float*)d_in[1];
  const float* value = (const float*)d_in[2];
  const float* ipw   = (const float*)d_in[3];   // (1536,1024)
  const float* ipb   = (const float*)d_in[4];   // (1536,)
  const float* opw   = (const float*)d_in[5];   // (1024,1024)
  const float* opb   = (const float*)d_in[6];   // (1024,)
  float* out = (float*)d_out;
  float* ws  = (float*)d_ws;

  float* XQ  = ws + OFF_XQ;
  float* XK  = ws + OFF_XK;
  float* XVt = ws + OFF_XVT;
  float* XO  = ws + OFF_XO;
  float* P   = ws + OFF_P;

  // in-projections (MFMA bf16x3)
  gemm_nt_mfma_k<<<dim3(16, 32), 256, 0, stream>>>(
      query, 1024, ipw, 1024, ipb, XQ, 1024, 1024);
  gemm_nt_mfma_k<<<dim3(4, 32), 256, 0, stream>>>(
      key, 1024, ipw + (size_t)1024 * 1024, 1024, ipb + 1024, XK, 256, 1024);
  proj_vt_k<<<dim3(16, 4, 2), 256, 0, stream>>>(
      ipw + (size_t)1280 * 1024, value, ipb + 1280, XVt);

  // scores + sigmoid + clip -> P
  scores_mfma_k<<<dim3(16, 16, 32), 256, 0, stream>>>(XQ, XK, P);

  // monotonic recurrence in place (one wave per z; 4-row affine-map passes)
  mono_rec_k<<<dim3(32), dim3(64), 0, stream>>>(P);

  // phi @ V -> XO (NT against transposed V)
  pv_mfma_k<<<dim3(1, 16, 32), 256, 0, stream>>>(P, XVt, XO);

  // out-projection
  gemm_nt_mfma_k<<<dim3(16, 32), 256, 0, stream>>>(
      XO, 1024, opw, 1024, opb, out, 1024, 1024);
}

// Round 2
// 647.459 us; speedup vs baseline: 1.2647x; 1.2647x over previous
//
#include <hip/hip_runtime.h>
#include <cstddef>
#include <cstdint>

// Problem constants: EMBED=1024, NUM_HEADS=16, GQA=4, KV_HEADS=4,
// HEAD_DIM=64, KV_EMBED=256, EPS=1e-3, B=2, T=1024.
#define TSEQ 1024

typedef __attribute__((ext_vector_type(8))) short short8;   // 8 bf16 = 4 VGPRs
typedef __attribute__((ext_vector_type(4))) float floatx4;  // MFMA acc

// Workspace layout (floats):
//  XQ : 2048 x 1024  (2M)
//  XK : 2048 x 256   (0.5M)
//  XVt: 2 x 256 x 1024 (0.5M)  -- V-projection TRANSPOSED: [b][h*64+c][j]
//  XO : 2048 x 1024  (2M)
//  P  : 32 x 1024x1024 (33.55M) -- probs/phi in DIAGONAL layout (see below)
static constexpr size_t OFF_XQ  = 0;
static constexpr size_t OFF_XK  = (size_t)2 * 1024 * 1024;
static constexpr size_t OFF_XVT = OFF_XK + (size_t)512 * 1024;
static constexpr size_t OFF_XO  = OFF_XVT + (size_t)512 * 1024;
static constexpr size_t OFF_P   = OFF_XO + (size_t)2 * 1024 * 1024;

// DIAGONAL LAYOUT (R7): logical cell (r, c) of each z's 1024x1024 matrix is
// stored at Pw[(r + (c>>4)) & 1023][c]. This makes the monotonic-recurrence
// wavefront (lane t owns cols [16t,16t+16), processes row r = s - t at step
// s) read and write ONE contiguous 4KB row (s & 1023) per step, perfectly
// coalesced and perfectly in-place: at step s every valid lane reads its
// 64B p-block and overwrites it with phi. The mod-1024 wrap is a bijection:
// blocks overwritten at step m (lanes t <= m) are exactly the blocks NOT
// consumed at step m+1024 (lanes t > m). Scores writes C and PV reads A
// through the same (row + (col>>4)) & 1023 shift; both keep their original
// per-instruction coalescing (the shift is constant within each 8-float
// staging segment and each 16-col store group).

// ---------------------------------------------------------------------------
// fp32 -> bf16 hi/lo split (RNE). x ≈ hi + lo with residual ~2^-17 |x|.
// ---------------------------------------------------------------------------
__device__ __forceinline__ void cvt_hi_lo(float x, unsigned short& hi,
                                          unsigned short& lo) {
  unsigned u = __float_as_uint(x);
  unsigned rh = (u + 0x7FFFu + ((u >> 16) & 1u)) & 0xFFFF0000u;
  hi = (unsigned short)(rh >> 16);
  float xl = x - __uint_as_float(rh);
  unsigned ul = __float_as_uint(xl);
  unsigned rl = ul + 0x7FFFu + ((ul >> 16) & 1u);
  lo = (unsigned short)(rl >> 16);
}

// ---------------------------------------------------------------------------
// Unified NT GEMM core, MFMA bf16x3 (R5-proven).
// ADIAG: A row index gets + (k>>4) & 1023 (reads diagonal-layout matrix).
// CDIAG: C row index gets + (col>>4) & 1023 (writes diagonal-layout matrix).
// ---------------------------------------------------------------------------
template <int EPI, int ADIAG, int CDIAG>
__device__ __forceinline__ void mfma_nt_core(
    const float* __restrict__ A, int lda,
    const float* __restrict__ B, int ldb,
    float* __restrict__ C, int ldc, int K,
    const float* __restrict__ bias)
{
  __shared__ __align__(16) unsigned short Ah[64][40];
  __shared__ __align__(16) unsigned short Al[64][40];
  __shared__ __align__(16) unsigned short Bh[64][40];
  __shared__ __align__(16) unsigned short Bl[64][40];

  const int bm = blockIdx.y << 6;
  const int bn = blockIdx.x << 6;
  const int tid  = threadIdx.x;
  const int lane = tid & 63;
  const int wave = tid >> 6;        // 0..3 -> row sub-tile
  const int m16  = lane & 15;
  const int quad = lane >> 4;

  const int srow = tid >> 2;        // staging: row 0..63
  const int skq  = (tid & 3) << 3;  // staging: k offset 0,8,16,24

  floatx4 acc[4];
#pragma unroll
  for (int c = 0; c < 4; ++c) acc[c] = (floatx4){0.f, 0.f, 0.f, 0.f};

  for (int k0 = 0; k0 < K; k0 += 32) {
    {
      const int kq = k0 + skq;
      int arow = bm + srow;
      if (ADIAG) arow = (arow + (kq >> 4)) & 1023;
      const float* ap = A + (size_t)arow * lda + kq;
      const float* bp = B + (size_t)(bn + srow) * ldb + kq;
      float av[8] __attribute__((aligned(16)));
      float bv[8] __attribute__((aligned(16)));
      *(float4*)&av[0] = *(const float4*)(ap);
      *(float4*)&av[4] = *(const float4*)(ap + 4);
      *(float4*)&bv[0] = *(const float4*)(bp);
      *(float4*)&bv[4] = *(const float4*)(bp + 4);
      short8 vah, valo, vbh, vblo;
#pragma unroll
      for (int e = 0; e < 8; ++e) {
        unsigned short h, l;
        cvt_hi_lo(av[e], h, l);
        vah[e] = (short)h; valo[e] = (short)l;
        cvt_hi_lo(bv[e], h, l);
        vbh[e] = (short)h; vblo[e] = (short)l;
      }
      *(short8*)&Ah[srow][skq] = vah;
      *(short8*)&Al[srow][skq] = valo;
      *(short8*)&Bh[srow][skq] = vbh;
      *(short8*)&Bl[srow][skq] = vblo;
    }
    __syncthreads();

    const int arow = (wave << 4) + m16;
    const short8 a_h = *(const short8*)&Ah[arow][quad << 3];
    const short8 a_l = *(const short8*)&Al[arow][quad << 3];
#pragma unroll
    for (int c = 0; c < 4; ++c) {
      const int brow = (c << 4) + m16;
      const short8 b_h = *(const short8*)&Bh[brow][quad << 3];
      const short8 b_l = *(const short8*)&Bl[brow][quad << 3];
      acc[c] = __builtin_amdgcn_mfma_f32_16x16x32_bf16(a_h, b_h, acc[c], 0, 0, 0);
      acc[c] = __builtin_amdgcn_mfma_f32_16x16x32_bf16(a_h, b_l, acc[c], 0, 0, 0);
      acc[c] = __builtin_amdgcn_mfma_f32_16x16x32_bf16(a_l, b_h, acc[c], 0, 0, 0);
    }
    __syncthreads();
  }

#pragma unroll
  for (int c = 0; c < 4; ++c) {
#pragma unroll
    for (int r = 0; r < 4; ++r) {
      const int row = (wave << 4) + (quad << 2) + r;
      const int col = (c << 4) + m16;
      float v = acc[c][r];
      if (EPI == 0) { if (bias) v += bias[bn + col]; }
      if (EPI == 1) { v += bias[bm + row]; }
      if (EPI == 2) {
        v = 1.0f / (1.0f + expf(-v));
        v = fminf(fmaxf(v, 0.001f), 0.999f);
      }
      int crow = bm + row;
      if (CDIAG) crow = (crow + ((bn + col) >> 4)) & 1023;
      C[(size_t)crow * ldc + (bn + col)] = v;
    }
  }
}

__global__ __launch_bounds__(256) void gemm_nt_mfma_k(
    const float* __restrict__ A, int lda, const float* __restrict__ W, int ldw,
    const float* __restrict__ bias, float* __restrict__ C, int ldc, int K)
{
  mfma_nt_core<0, 0, 0>(A, lda, W, ldw, C, ldc, K, bias);
}

__global__ __launch_bounds__(256) void proj_vt_k(
    const float* __restrict__ vw, const float* __restrict__ value,
    const float* __restrict__ vb, float* __restrict__ XVt)
{
  const int b = blockIdx.z;
  mfma_nt_core<1, 0, 0>(vw, 1024, value + ((size_t)b << 20), 1024,
                        XVt + (size_t)b * 256 * 1024, 1024, 1024, vb);
}

// scores: writes P in DIAGONAL layout (CDIAG=1)
__global__ __launch_bounds__(256) void scores_mfma_k(
    const float* __restrict__ XQ, const float* __restrict__ XK,
    float* __restrict__ P)
{
  const int z = blockIdx.z;
  const int b = z >> 4;
  mfma_nt_core<2, 0, 1>(XQ + ((size_t)b << 20) + ((size_t)(z & 15) << 6), 1024,
                        XK + (size_t)b * TSEQ * 256 + ((size_t)(z & 3) << 6), 256,
                        P + ((size_t)z << 20), 1024, 64, nullptr);
}

// pv: reads phi (A matrix) from DIAGONAL layout (ADIAG=1)
__global__ __launch_bounds__(256) void pv_mfma_k(
    const float* __restrict__ P, const float* __restrict__ XVt,
    float* __restrict__ XO)
{
  const int z = blockIdx.z;
  const int b = z >> 4;
  mfma_nt_core<0, 1, 0>(P + ((size_t)z << 20), 1024,
                        XVt + (size_t)b * 256 * 1024 + (size_t)(z & 3) * 64 * 1024, 1024,
                        XO + ((size_t)b << 20) + ((size_t)(z & 15) << 6), 1024,
                        1024, nullptr);
}

// ---------------------------------------------------------------------------
// Monotonic recurrence, DIAGONAL-WAVEFRONT systolic (R7). ONE WAVE per z.
// Lane t owns columns [16t, 16t+16). At step s, lane t processes row
// r = s - t directly via the raw recurrence
//   phi[r,c] = b[c] + (1 - p[r,c-1]) * phi[r,c-1],   b[c] = p[r-1,c]*phi[r-1,c]
// (b and phi[r-1] live in this lane's registers from step s-1). The only
// cross-lane traffic is phi[r,16t-1] and p[r,16t-1], both produced by lane
// t-1 at step s-1 -> exactly 2 __shfl_up(.,1) per 1024-column row, replacing
// the 30+ Kogge-Stone shuffle-values per 2 rows of the scan formulation
// (R6 measured: cost scales with total shuffled values, ~45cy each).
// Memory: diagonal layout makes each step read+write ONE contiguous 4KB
// storage row, in place (see layout comment above). p loads are prefetched
// 4 steps (~500cy) ahead through a 4-deep register pipeline.
// Cross-lane = __shfl only (DPP failed 3x on gfx950 -- permanently banned).
// ---------------------------------------------------------------------------
__global__ __launch_bounds__(64) void mono_rec_k(float* __restrict__ P)
{
  const int z = blockIdx.x;
  float* __restrict__ Pz = P + ((size_t)z << 20);
  const int t = threadIdx.x;     // lane 0..63
  const int col0 = t << 4;       // first owned column

  float b[16];                   // carry: b[c] = phi[r-1,c] * p[r-1,c]
#pragma unroll
  for (int c = 0; c < 16; ++c) b[c] = 0.0f;
  float p15h = 0.0f, phi15h = 0.0f;   // col-15 values held for lane t+1

  float pbuf[4][16];             // 4-deep prefetch pipeline (static idx only)

  // prologue: prefetch storage rows for steps 0..3
#pragma unroll
  for (int j = 0; j < 4; ++j) {
    const float* lp = Pz + ((size_t)j << 10) + col0;
#pragma unroll
    for (int q = 0; q < 4; ++q)
      *(float4*)&pbuf[j][4 * q] = *(const float4*)(lp + 4 * q);
  }

  // steps 0..1087 (1087 = 1023 + 64 - 1 + 1 pad; step 1087 is all-invalid)
  for (int sb = 0; sb < 1088; sb += 4) {
#pragma unroll
    for (int j = 0; j < 4; ++j) {
      const int s = sb + j;

      // consume this step's p-block
      float p[16];
#pragma unroll
      for (int c = 0; c < 16; ++c) p[c] = pbuf[j][c];

      // refill pipeline: prefetch step s+4's storage row
      {
        const float* lp = Pz + ((size_t)((s + 4) & 1023) << 10) + col0;
#pragma unroll
        for (int q = 0; q < 4; ++q)
          *(float4*)&pbuf[j][4 * q] = *(const float4*)(lp + 4 * q);
      }

      // boundary values from lane t-1 (its row-r col 16t-1, finished at s-1).
      // Executed unconditionally so source lanes are active in the shuffle.
      const float phiL = __shfl_up(phi15h, 1);
      const float pL   = __shfl_up(p15h, 1);

      const int r = s - t;
      if (r >= 0 && r < 1024) {
        float phi[16];
        if (r == 0) {
          // phi[0] = onehot(col 0)
#pragma unroll
          for (int c = 0; c < 16; ++c) phi[c] = 0.0f;
          if (t == 0) phi[0] = 1.0f;
        } else {
          const float H0 = (t == 0) ? 0.0f : (1.0f - pL);
          float x = fmaf(H0, phiL, b[0]);
          phi[0] = x;
#pragma unroll
          for (int c = 1; c < 16; ++c) {
            x = fmaf(1.0f - p[c - 1], x, b[c]);
            phi[c] = x;
          }
        }
        // next-row carry + neighbor holds
#pragma unroll
        for (int c = 0; c < 16; ++c) b[c] = phi[c] * p[c];
        p15h  = p[15];
        phi15h = phi[15];
        // write phi over p, same cells (in-place, coalesced)
        float* spr = Pz + ((size_t)(s & 1023) << 10) + col0;
#pragma unroll
        for (int q = 0; q < 4; ++q)
          *(float4*)(spr + 4 * q) = *(float4*)&phi[4 * q];
      }
    }
  }
}

// ---------------------------------------------------------------------------
extern "C" void kernel_launch(void* const* d_in, const int* in_sizes, int n_in,
                              void* d_out, int out_size, void* d_ws, size_t ws_size,
                              hipStream_t stream)
{
  const float* query = (const float*)d_in[0];
  const float* key   = (const float*)d_in[1];
  const float* value = (const float*)d_in[2];
  const float* ipw   = (const float*)d_in[3];   // (1536,1024)
  const float* ipb   = (const float*)d_in[4];   // (1536,)
  const float* opw   = (const float*)d_in[5];   // (1024,1024)
  const float* opb   = (const float*)d_in[6];   // (1024,)
  float* out = (float*)d_out;
  float* ws  = (float*)d_ws;

  float* XQ  = ws + OFF_XQ;
  float* XK  = ws + OFF_XK;
  float* XVt = ws + OFF_XVT;
  float* XO  = ws + OFF_XO;
  float* P   = ws + OFF_P;

  // in-projections (MFMA bf16x3)
  gemm_nt_mfma_k<<<dim3(16, 32), 256, 0, stream>>>(
      query, 1024, ipw, 1024, ipb, XQ, 1024, 1024);
  gemm_nt_mfma_k<<<dim3(4, 32), 256, 0, stream>>>(
      key, 1024, ipw + (size_t)1024 * 1024, 1024, ipb + 1024, XK, 256, 1024);
  proj_vt_k<<<dim3(16, 4, 2), 256, 0, stream>>>(
      ipw + (size_t)1280 * 1024, value, ipb + 1280, XVt);

  // scores + sigmoid + clip -> P (diagonal layout)
  scores_mfma_k<<<dim3(16, 16, 32), 256, 0, stream>>>(XQ, XK, P);

  // monotonic recurrence in place (diagonal wavefront, one wave per z)
  mono_rec_k<<<dim3(32), dim3(64), 0, stream>>>(P);

  // phi @ V -> XO (NT against transposed V; A read through diagonal map)
  pv_mfma_k<<<dim3(1, 16, 32), 256, 0, stream>>>(P, XVt, XO);

  // out-projection
  gemm_nt_mfma_k<<<dim3(16, 32), 256, 0, stream>>>(
      XO, 1024, opw, 1024, opb, out, 1024, 1024);
}